// Round 7
// baseline (383.967 us; speedup 1.0000x reference)
//
#include <hip/hip_runtime.h>
#include <math.h>
#include <limits.h>

#define TPB   256
#define TILE  1024          // items per block-tile (256 thr x 4 rounds)
#define RNDS  4
#define MAXT  2048
#define MAXK  1024
#define MAXW  29            // max span width in this problem (W=30 -> w<=29)
#define BATCH 1024          // greedy candidates per round (4 per thread)

// ===========================================================================
// Kernel A: fused key-build + 4-pass LSD radix argsort (60 blocks, grid bars)
// ===========================================================================
struct SortSM {
  union {
    unsigned h[4 * 256];                  // P0: 4 pass histograms
    struct {
      unsigned wcnt[4][256];              // [wave][digit] (also scan scratch)
      unsigned runCnt[256];
      unsigned baseL[256];
    } pass;
  };
};

// Device-scope grid barrier. SAFE: grid (<=60 blocks) fully co-resident on
// 256 CUs. ctr[] zeroed by memset node each launch. (Original RMW-poll form:
// load-poll variant measured null in R6.)
__device__ inline void gbar(unsigned* ctr, int idx, unsigned nblk) {
  __syncthreads();
  if (threadIdx.x == 0) {
    __threadfence();
    atomicAdd(&ctr[idx], 1u);
    while (atomicAdd(&ctr[idx], 0u) < nblk) { __builtin_amdgcn_s_sleep(8); }
    __threadfence();
  }
  __syncthreads();
}

__global__ void __launch_bounds__(TPB, 1) sort_kernel(
    const float* __restrict__ scores, const float* __restrict__ mask,
    int N, int nT, unsigned* ctr, unsigned* ghist, unsigned* tileCnt,
    unsigned* keysA, unsigned* keysB, int* idxA, int* idxB) {
  __shared__ SortSM s;
  __shared__ unsigned base4[4][256];      // per-block copy of scanned bases
  const int tid = threadIdx.x;
  const int lane = tid & 63;
  const int wave = tid >> 6;

  // ---- P0: build keys + all 4 histograms in one read ----
  for (int j = tid; j < 1024; j += TPB) s.h[j] = 0;
  __syncthreads();
  {
    const int tile0 = blockIdx.x * TILE;
    for (int r = 0; r < RNDS; ++r) {
      int i = tile0 + r * 256 + tid;
      if (i < N) {
        float kf = scores[i] + logf(mask[i]);          // mask==1 -> +0 exact
        unsigned u = __float_as_uint(kf);
        u = (u & 0x80000000u) ? ~u : (u | 0x80000000u);
        u = ~u;                                        // descending order
        keysA[i] = u;
        atomicAdd(&s.h[(u & 255u)], 1u);
        atomicAdd(&s.h[256 + ((u >> 8) & 255u)], 1u);
        atomicAdd(&s.h[512 + ((u >> 16) & 255u)], 1u);
        atomicAdd(&s.h[768 + (u >> 24)], 1u);
      }
    }
    __syncthreads();
    for (int j = tid; j < 1024; j += TPB)
      if (s.h[j]) atomicAdd(&ghist[j], s.h[j]);
  }
  gbar(ctr, 0, nT);

  // ---- every block scans all 4 digit histograms locally (no grid phase) ----
  for (int p = 0; p < 4; ++p) {
    unsigned v = ghist[p * 256 + tid];
    unsigned* A = s.pass.wcnt[0];
    unsigned* B = s.pass.wcnt[1];
    A[tid] = v;
    __syncthreads();
    for (int off = 1; off < 256; off <<= 1) {
      B[tid] = A[tid] + ((tid >= off) ? A[tid - off] : 0u);
      __syncthreads();
      unsigned* t = A; A = B; B = t;
    }
    base4[p][tid] = A[tid] - v;            // exclusive scan
    __syncthreads();
  }

  // ---- 4 fused rank/scatter radix passes ----
  for (int p = 0; p < 4; ++p) {
    const unsigned* srck = (p & 1) ? keysB : keysA;
    const int*      srci = (p & 1) ? idxB : idxA;     // p==0: payload = i
    unsigned*       dstk = (p & 1) ? keysA : keysB;
    int*            dsti = (p & 1) ? idxA : idxB;
    const int shift = 8 * p;
    const int tile0 = blockIdx.x * TILE;

    s.pass.runCnt[tid] = 0;
    unsigned mykey[RNDS]; int mypay[RNDS]; unsigned mypos[RNDS]; bool myval[RNDS];
    #pragma unroll
    for (int r = 0; r < RNDS; ++r) {
      __syncthreads();
      s.pass.wcnt[0][tid] = 0; s.pass.wcnt[1][tid] = 0;
      s.pass.wcnt[2][tid] = 0; s.pass.wcnt[3][tid] = 0;
      __syncthreads();
      int i = tile0 + r * 256 + tid;
      bool v = (i < N);
      unsigned key = v ? srck[i] : 0u;
      int pay = v ? ((p == 0) ? i : srci[i]) : 0;
      unsigned d = (key >> shift) & 255u;
      unsigned long long mm = __ballot(v);     // stable rank within wave
      #pragma unroll
      for (int b = 0; b < 8; ++b) {
        unsigned long long bb = __ballot((d >> b) & 1u);
        mm &= ((d >> b) & 1u) ? bb : ~bb;
      }
      int rank = (int)__popcll(mm & ((1ull << lane) - 1ull));
      if (v && rank == 0) s.pass.wcnt[wave][d] = (unsigned)__popcll(mm);
      __syncthreads();
      unsigned run0 = s.pass.runCnt[tid];
      unsigned run = 0;
      #pragma unroll
      for (int w2 = 0; w2 < 4; ++w2) {
        unsigned c = s.pass.wcnt[w2][tid];
        s.pass.wcnt[w2][tid] = run0 + run;
        run += c;
      }
      s.pass.runCnt[tid] = run0 + run;
      __syncthreads();
      mykey[r] = key; mypay[r] = pay; myval[r] = v;
      mypos[r] = v ? (s.pass.wcnt[wave][d] + (unsigned)rank) : 0u;
    }
    __syncthreads();
    tileCnt[blockIdx.x * 256 + tid] = s.pass.runCnt[tid];
    gbar(ctr, 1 + 2 * p, nT);

    unsigned baseacc = base4[p][tid];
    for (int t = 0; t < blockIdx.x; ++t)
      baseacc += tileCnt[t * 256 + tid];
    s.pass.baseL[tid] = baseacc;
    __syncthreads();
    #pragma unroll
    for (int r = 0; r < RNDS; ++r) {
      if (myval[r]) {
        unsigned d = (mykey[r] >> shift) & 255u;
        unsigned pos = s.pass.baseL[d] + mypos[r];
        dstk[pos] = mykey[r];
        dsti[pos] = mypay[r];
      }
    }
    if (p < 3) gbar(ctr, 2 + 2 * p, nT);
  }
  // final order in idxA (A->B->A->B->A)
}

// ===========================================================================
// Kernel B: batched-speculative greedy (1 block, 256 threads) + epilogue.
// v7: crossing state = ONE rejection bitmap R[start] (bit w = span (s,s+w)
//     crosses an accepted span), kept ALWAYS FRESH by wave-parallel per-accept
//     updates inside the resolver (64 lanes cover the <=59 affected starts).
//     Pre-check AND resolver re-check are each 1 LDS read. tab/tabP deleted.
// ===========================================================================
__global__ void __launch_bounds__(TPB, 1) greedy_kernel(
    const int2* __restrict__ spans2, const int* __restrict__ spans,
    const float* __restrict__ scores, const int* __restrict__ order,
    const int* __restrict__ tnum_p, const int* __restrict__ keep_p,
    float* __restrict__ out, int N) {
  __shared__ unsigned R[MAXT];                 // rejection bitmap
  __shared__ unsigned long long acc[MAXK];
  __shared__ unsigned long long surv[BATCH];
  __shared__ unsigned long long Cmat[BATCH];   // in-group crossing rows
  __shared__ int wvs[16];                      // survivor counts [quarter][wave]
  __shared__ int gcnt;

  const int tid = threadIdx.x;
  const int lane = tid & 63;
  const int wave = tid >> 6;
  const int T  = tnum_p[0];
  const int k0 = keep_p[0];
  const int k  = (k0 < MAXK) ? k0 : MAXK;

  for (int t = tid; t < MAXT; t += TPB) R[t] = 0u;
  if (tid == 0) gcnt = 0;
  __syncthreads();

  // Each thread owns candidates q*256+tid (q=0..3) of every round.
  // ids prefetched 2 rounds ahead, spans 1 round ahead. Static indexing only.
  int cc[4], cs[4], ce[4], nn[4];
  #pragma unroll
  for (int q = 0; q < 4; ++q) {
    cc[q] = -1; nn[q] = -1; cs[q] = 0; ce[q] = 0;
    int i0 = q * 256 + tid;
    if (i0 < N) cc[q] = order[i0];
    int i1 = BATCH + q * 256 + tid;
    if (i1 < N) nn[q] = order[i1];
    if (cc[q] >= 0) { int2 sp = spans2[cc[q]]; cs[q] = sp.x; ce[q] = sp.y; }
  }

  int cnt = 0;
  for (int c0 = 0; c0 < N && cnt < k; c0 += BATCH) {
    // ---- prefetch next-round spans + next-next-round ids ----
    int pc[4], ps[4], pe[4];
    #pragma unroll
    for (int q = 0; q < 4; ++q) {
      pc[q] = nn[q]; ps[q] = 0; pe[q] = 0;
      if (pc[q] >= 0) { int2 sp = spans2[pc[q]]; ps[q] = sp.x; pe[q] = sp.y; }
      int i2 = c0 + 2 * BATCH + q * 256 + tid;
      nn[q] = (i2 < N) ? order[i2] : -1;
    }

    // ---- O(1) pre-check: 1 LDS read per candidate (R fresh thru last round) --
    bool ok[4];
    unsigned long long bal[4];
    #pragma unroll
    for (int q = 0; q < 4; ++q) {
      ok[q] = (cc[q] >= 0) && !((R[cs[q]] >> (unsigned)(ce[q] - cs[q])) & 1u);
      bal[q] = __ballot(ok[q]);
      if (lane == 0) wvs[q * 4 + wave] = (int)__popcll(bal[q]);
    }
    __syncthreads();
    int qtot0 = wvs[0]  + wvs[1]  + wvs[2]  + wvs[3];
    int qtot1 = wvs[4]  + wvs[5]  + wvs[6]  + wvs[7];
    int qtot2 = wvs[8]  + wvs[9]  + wvs[10] + wvs[11];
    int qtot3 = wvs[12] + wvs[13] + wvs[14] + wvs[15];
    int ns = qtot0 + qtot1 + qtot2 + qtot3;

    if (ns > 0) {              // uniform branch: all threads agree on ns
      // ---- order-preserving survivor compression -> LDS (1024-wide) ----
      int qbase[4] = {0, qtot0, qtot0 + qtot1, qtot0 + qtot1 + qtot2};
      #pragma unroll
      for (int q = 0; q < 4; ++q) {
        if (ok[q]) {
          int wb = qbase[q];
          for (int w2 = 0; w2 < wave; ++w2) wb += wvs[q * 4 + w2];
          int pos = wb + (int)__popcll(bal[q] & ((1ull << lane) - 1ull));
          surv[pos] = ((unsigned long long)(unsigned)cs[q] << 48)
                    | ((unsigned long long)(unsigned)ce[q] << 32)
                    | (unsigned)cc[q];
        }
      }
      __syncthreads();

      // ---- parallel in-group crossing-matrix precompute (table-independent) ----
      for (int v = tid; v < ns; v += TPB) {
        unsigned long long pk = surv[v];
        int gs = (int)(pk >> 48), ge = (int)((pk >> 32) & 0xFFFFu);
        int gbase = v & ~63;
        int m = ns - gbase; if (m > 64) m = 64;
        unsigned long long C = 0;
        for (int j = 0; j < m; ++j) {
          unsigned long long pj = surv[gbase + j];
          int sj = (int)(pj >> 48), ej = (int)((pj >> 32) & 0xFFFFu);
          bool cr = (gs < sj && sj <= ge && ej > ge) ||
                    (sj < gs && gs <= ej && ej < ge);
          C |= (unsigned long long)cr << j;
        }
        Cmat[v] = C;
      }
      __syncthreads();

      // ---- wave-0 resolution, 64 survivors at a time ----
      if (tid < 64) {
        for (int g = 0; g < ns && cnt < k; g += 64) {
          int m = ns - g; if (m > 64) m = 64;
          bool act = lane < m;
          int gs = 0, ge = 0, gc = 0;
          unsigned long long C = 0;
          if (act) {
            unsigned long long pk = surv[g + lane];
            gs = (int)(pk >> 48);
            ge = (int)((pk >> 32) & 0xFFFFu);
            gc = (int)(unsigned)pk;
            C  = Cmat[g + lane];
          }
          // re-check vs ALWAYS-FRESH R: 1 LDS read
          bool pre = act && !((R[gs] >> (unsigned)(ge - gs)) & 1u);
          unsigned long long preB = __ballot(pre);
          if (preB == 0ull) continue;
          int np = (int)__popcll(preB);
          unsigned long long lower = (1ull << lane) - 1ull;
          unsigned long long accm;
          int cnt0g = cnt;
          if (np == 1) {                       // single-survivor fast path
            accm = preB;
            cnt += 1;
          } else {
            if (cnt + np <= k) {
              // bulk: accept all with no earlier *surviving* in-group crosser
              bool easy = pre && ((C & lower & preB) == 0ull);
              accm = __ballot(easy);
              unsigned long long rem = preB & ~accm;
              while (rem) {
                unsigned long long kmask = __ballot((C & accm & lower) != 0ull);
                int j = __ffsll((long long)rem) - 1;
                rem &= rem - 1;
                if (!((kmask >> j) & 1ull)) accm |= 1ull << j;
              }
              cnt += (int)__popcll(accm);
            } else {
              // k-cap mode: strict serial order incl. count limit
              accm = 0ull;
              unsigned long long rem = preB;
              while (rem && cnt < k) {
                unsigned long long kmask = __ballot((C & accm & lower) != 0ull);
                int j = __ffsll((long long)rem) - 1;
                rem &= rem - 1;
                if (!((kmask >> j) & 1ull)) { accm |= 1ull << j; cnt++; }
              }
            }
          }
          bool accme = ((accm >> lane) & 1ull) != 0ull;
          if (accme) {
            int rank = (int)__popcll(accm & lower);
            acc[cnt0g + rank] =
                ((unsigned long long)(unsigned)(gs * T + ge) << 32) | (unsigned)gc;
          }
          // ---- wave-parallel R update, one accept at a time (uniform loop) --
          // accepted (as,ae), ae>as, rejects:
          //   cond1: s in [as-29, as-1], w in [as-s, ae-1-s]
          //   cond2: s in [as+1, ae],    w in [ae-s+1, min(29, T-1-s)]
          unsigned long long upd = accm & __ballot(ge > gs);
          while (upd) {
            int j = __ffsll((long long)upd) - 1;
            upd &= upd - 1;
            int as = __shfl(gs, j);
            int ae = __shfl(ge, j);
            int s = as - MAXW + lane;          // 64 lanes cover <=59 starts
            if (s >= 0 && s <= ae && s != as) {
              unsigned mmask = 0u;
              if (s < as) {
                int l1 = as - s;
                int h1 = ae - 1 - s; if (h1 > MAXW) h1 = MAXW;
                if (h1 >= l1)
                  mmask = ((1u << (h1 + 1)) - 1u) & ~((1u << l1) - 1u);
              } else {
                int l2 = ae - s + 1;
                int h2 = T - 1 - s; if (h2 > MAXW) h2 = MAXW;
                if (h2 >= l2)
                  mmask = ((1u << (h2 + 1)) - 1u) & ~((1u << l2) - 1u);
              }
              if (mmask) atomicOr(&R[s], mmask);
            }
          }
        }
        if (lane == 0) gcnt = cnt;
      }
      __syncthreads();
      cnt = gcnt;
    }

    #pragma unroll
    for (int q = 0; q < 4; ++q) { cc[q] = pc[q]; cs[q] = ps[q]; ce[q] = pe[q]; }
  }

  // ---- bitonic ascending sort of acc[0..cnt) by (s*T+e, cand) ----
  int M = 2;
  while (M < cnt) M <<= 1;
  for (int j = tid; j < M; j += TPB)
    if (j >= cnt) acc[j] = ~0ull;
  __syncthreads();
  for (int kk = 2; kk <= M; kk <<= 1) {
    for (int jj = kk >> 1; jj > 0; jj >>= 1) {
      for (int i3 = tid; i3 < M; i3 += TPB) {
        int ixj = i3 ^ jj;
        if (ixj > i3) {
          unsigned long long a = acc[i3], b = acc[ixj];
          bool up = ((i3 & kk) == 0);
          if ((a > b) == up) { acc[i3] = b; acc[ixj] = a; }
        }
      }
      __syncthreads();
    }
  }

  // ---- epilogue: scores | idx | spans | valid, all f32 ----
  for (int j = tid; j < k0; j += TPB) {
    if (j < cnt) {
      int cand = (int)(acc[j] & 0xFFFFFFFFu);
      out[j]                  = scores[cand];
      out[k0 + j]             = (float)cand;
      out[2 * k0 + 2 * j]     = (float)spans[2 * cand];
      out[2 * k0 + 2 * j + 1] = (float)spans[2 * cand + 1];
      out[4 * k0 + j]         = 1.0f;
    } else {
      out[j]                  = 0.0f;
      out[k0 + j]             = 0.0f;
      out[2 * k0 + 2 * j]     = 0.0f;
      out[2 * k0 + 2 * j + 1] = 0.0f;
      out[4 * k0 + j]         = 0.0f;
    }
  }
}

extern "C" void kernel_launch(void* const* d_in, const int* in_sizes, int n_in,
                              void* d_out, int out_size, void* d_ws, size_t ws_size,
                              hipStream_t stream) {
  const int*   spans  = (const int*)d_in[0];
  const float* scores = (const float*)d_in[1];
  const float* mask   = (const float*)d_in[2];
  const int*   tnum   = (const int*)d_in[3];
  const int*   keep   = (const int*)d_in[4];
  const int N = in_sizes[1];
  const int nT = (N + TILE - 1) / TILE;   // 60 for N=61440

  // ws: ctr[32] | ghist[4*256] | tileCnt[nT*256] | keysA | keysB | idxA | idxB
  unsigned* ctr     = (unsigned*)d_ws;
  unsigned* ghist   = ctr + 32;
  unsigned* tileCnt = ghist + 4 * 256;
  unsigned* keysA   = tileCnt + (size_t)nT * 256;
  unsigned* keysB   = keysA + N;
  int*      idxA    = (int*)(keysB + N);
  int*      idxB    = idxA + N;
  float*    out     = (float*)d_out;

  hipMemsetAsync(ctr, 0, (32 + 4 * 256) * sizeof(unsigned), stream);

  sort_kernel<<<nT, TPB, 0, stream>>>(scores, mask, N, nT, ctr, ghist,
                                      tileCnt, keysA, keysB, idxA, idxB);
  greedy_kernel<<<1, TPB, 0, stream>>>((const int2*)spans, spans, scores,
                                       idxA, tnum, keep, out, N);
}

// Round 8
// 325.863 us; speedup vs baseline: 1.1783x; 1.1783x over previous
//
#include <hip/hip_runtime.h>
#include <math.h>
#include <limits.h>

#define TPB   256
#define TILE  1024          // items per block-tile (256 thr x 4 rounds)
#define RNDS  4
#define MAXT  2048
#define TPAD  64            // pad so unconditional reads past e stay in-bounds
#define MAXK  1024
#define MAXW  29            // max span width in this problem (W=30 -> w<=29)
#define BATCH 1024          // greedy candidates per round (4 per thread)

// ===========================================================================
// Kernel A: fused key-build + 4-pass LSD radix argsort (60 blocks, grid bars)
// ===========================================================================
struct SortSM {
  union {
    unsigned h[4 * 256];                  // P0: 4 pass histograms
    struct {
      unsigned wcnt[4][256];              // [wave][digit] (also scan scratch)
      unsigned runCnt[256];
      unsigned baseL[256];
    } pass;
  };
};

// Device-scope grid barrier. SAFE: grid (<=60 blocks) fully co-resident on
// 256 CUs. ctr[] zeroed by memset node each launch.
__device__ inline void gbar(unsigned* ctr, int idx, unsigned nblk) {
  __syncthreads();
  if (threadIdx.x == 0) {
    __threadfence();
    atomicAdd(&ctr[idx], 1u);
    while (atomicAdd(&ctr[idx], 0u) < nblk) { __builtin_amdgcn_s_sleep(8); }
    __threadfence();
  }
  __syncthreads();
}

__global__ void __launch_bounds__(TPB, 1) sort_kernel(
    const float* __restrict__ scores, const float* __restrict__ mask,
    int N, int nT, unsigned* ctr, unsigned* ghist, unsigned* tileCnt,
    unsigned* keysA, unsigned* keysB, int* idxA, int* idxB) {
  __shared__ SortSM s;
  __shared__ unsigned base4[4][256];      // per-block copy of scanned bases
  const int tid = threadIdx.x;
  const int lane = tid & 63;
  const int wave = tid >> 6;

  // ---- P0: build keys + all 4 histograms in one read ----
  for (int j = tid; j < 1024; j += TPB) s.h[j] = 0;
  __syncthreads();
  {
    const int tile0 = blockIdx.x * TILE;
    for (int r = 0; r < RNDS; ++r) {
      int i = tile0 + r * 256 + tid;
      if (i < N) {
        float kf = scores[i] + logf(mask[i]);          // mask==1 -> +0 exact
        unsigned u = __float_as_uint(kf);
        u = (u & 0x80000000u) ? ~u : (u | 0x80000000u);
        u = ~u;                                        // descending order
        keysA[i] = u;
        atomicAdd(&s.h[(u & 255u)], 1u);
        atomicAdd(&s.h[256 + ((u >> 8) & 255u)], 1u);
        atomicAdd(&s.h[512 + ((u >> 16) & 255u)], 1u);
        atomicAdd(&s.h[768 + (u >> 24)], 1u);
      }
    }
    __syncthreads();
    for (int j = tid; j < 1024; j += TPB)
      if (s.h[j]) atomicAdd(&ghist[j], s.h[j]);
  }
  gbar(ctr, 0, nT);

  // ---- every block scans all 4 digit histograms locally (no grid phase) ----
  for (int p = 0; p < 4; ++p) {
    unsigned v = ghist[p * 256 + tid];
    unsigned* A = s.pass.wcnt[0];
    unsigned* B = s.pass.wcnt[1];
    A[tid] = v;
    __syncthreads();
    for (int off = 1; off < 256; off <<= 1) {
      B[tid] = A[tid] + ((tid >= off) ? A[tid - off] : 0u);
      __syncthreads();
      unsigned* t = A; A = B; B = t;
    }
    base4[p][tid] = A[tid] - v;            // exclusive scan
    __syncthreads();
  }

  // ---- 4 fused rank/scatter radix passes ----
  for (int p = 0; p < 4; ++p) {
    const unsigned* srck = (p & 1) ? keysB : keysA;
    const int*      srci = (p & 1) ? idxB : idxA;     // p==0: payload = i
    unsigned*       dstk = (p & 1) ? keysA : keysB;
    int*            dsti = (p & 1) ? idxA : idxB;
    const int shift = 8 * p;
    const int tile0 = blockIdx.x * TILE;

    s.pass.runCnt[tid] = 0;
    unsigned mykey[RNDS]; int mypay[RNDS]; unsigned mypos[RNDS]; bool myval[RNDS];
    #pragma unroll
    for (int r = 0; r < RNDS; ++r) {
      __syncthreads();
      s.pass.wcnt[0][tid] = 0; s.pass.wcnt[1][tid] = 0;
      s.pass.wcnt[2][tid] = 0; s.pass.wcnt[3][tid] = 0;
      __syncthreads();
      int i = tile0 + r * 256 + tid;
      bool v = (i < N);
      unsigned key = v ? srck[i] : 0u;
      int pay = v ? ((p == 0) ? i : srci[i]) : 0;
      unsigned d = (key >> shift) & 255u;
      unsigned long long mm = __ballot(v);     // stable rank within wave
      #pragma unroll
      for (int b = 0; b < 8; ++b) {
        unsigned long long bb = __ballot((d >> b) & 1u);
        mm &= ((d >> b) & 1u) ? bb : ~bb;
      }
      int rank = (int)__popcll(mm & ((1ull << lane) - 1ull));
      if (v && rank == 0) s.pass.wcnt[wave][d] = (unsigned)__popcll(mm);
      __syncthreads();
      unsigned run0 = s.pass.runCnt[tid];
      unsigned run = 0;
      #pragma unroll
      for (int w2 = 0; w2 < 4; ++w2) {
        unsigned c = s.pass.wcnt[w2][tid];
        s.pass.wcnt[w2][tid] = run0 + run;
        run += c;
      }
      s.pass.runCnt[tid] = run0 + run;
      __syncthreads();
      mykey[r] = key; mypay[r] = pay; myval[r] = v;
      mypos[r] = v ? (s.pass.wcnt[wave][d] + (unsigned)rank) : 0u;
    }
    __syncthreads();
    tileCnt[blockIdx.x * 256 + tid] = s.pass.runCnt[tid];
    gbar(ctr, 1 + 2 * p, nT);

    unsigned baseacc = base4[p][tid];
    for (int t = 0; t < blockIdx.x; ++t)
      baseacc += tileCnt[t * 256 + tid];
    s.pass.baseL[tid] = baseacc;
    __syncthreads();
    #pragma unroll
    for (int r = 0; r < RNDS; ++r) {
      if (myval[r]) {
        unsigned d = (mykey[r] >> shift) & 255u;
        unsigned pos = s.pass.baseL[d] + mypos[r];
        dstk[pos] = mykey[r];
        dsti[pos] = mypay[r];
      }
    }
    if (p < 3) gbar(ctr, 2 + 2 * p, nT);
  }
  // final order in idxA (A->B->A->B->A)
}

// ===========================================================================
// Kernel B: batched-speculative greedy (1 block, 256 threads) + epilogue.
// v8 = v3 resolver (tab/tabP dirty-recheck, per-lane O(1) updates) +
//      O(1) round-entry pre-check via R bitmap + BATCHED round-end R update
//      (parallel over accept x offset: ~8 independent LDS ops/thread/round).
// ===========================================================================
__device__ inline bool precheck30(const unsigned* tabP, int cc, int cs, int ce) {
  if (cc < 0) return false;
  int w = ce - cs;
  bool crossed = false;
  #pragma unroll
  for (int off = 0; off <= MAXW; ++off) {
    unsigned tv = tabP[cs + off];
    crossed |= ((off >= 1) & (off <= w) & ((tv & 0xFFFFu) > (unsigned)(ce + 1)))
             | ((off < w) & ((tv >> 16) < (unsigned)cs));
  }
  for (int off = MAXW + 1; off <= w; ++off) {   // generic fallback (unused)
    unsigned tv = tabP[cs + off];
    crossed |= ((tv & 0xFFFFu) > (unsigned)(ce + 1));
    if (off < w) crossed |= ((tv >> 16) < (unsigned)cs);
  }
  return !crossed;
}

__global__ void __launch_bounds__(TPB, 1) greedy_kernel(
    const int2* __restrict__ spans2, const int* __restrict__ spans,
    const float* __restrict__ scores, const int* __restrict__ order,
    const int* __restrict__ tnum_p, const int* __restrict__ keep_p,
    float* __restrict__ out, int N) {
  __shared__ unsigned tabP[MAXT + TPAD];  // hi16 = e2s(enc), lo16 = s2e+1
  __shared__ int2 tab[MAXT + TPAD];       // authoritative: .x=s2e, .y=e2s
  __shared__ unsigned R[MAXT];            // rejection bitmap (fresh at round entry)
  __shared__ unsigned long long acc[MAXK];
  __shared__ unsigned racc_s[MAXK];       // accepted (s<<16|e), for R update
  __shared__ unsigned long long surv[BATCH];
  __shared__ unsigned long long Cmat[BATCH];   // in-group crossing rows
  __shared__ int wvs[16];                      // survivor counts [quarter][wave]
  __shared__ int gcnt;

  const int tid = threadIdx.x;
  const int lane = tid & 63;
  const int wave = tid >> 6;
  const int T  = tnum_p[0];
  const int k0 = keep_p[0];
  const int k  = (k0 < MAXK) ? k0 : MAXK;

  for (int t = tid; t < MAXT + TPAD; t += TPB) {
    tab[t] = make_int2(-1, INT_MAX);
    tabP[t] = 0xFFFF0000u;               // s2e+1 = 0, e2s_enc = 0xFFFF
    if (t < MAXT) R[t] = 0u;
  }
  if (tid == 0) gcnt = 0;
  __syncthreads();

  // Each thread owns candidates q*256+tid (q=0..3) of every round.
  // ids prefetched 2 rounds ahead, spans 1 round ahead. Static indexing only.
  int cc[4], cs[4], ce[4], nn[4];
  #pragma unroll
  for (int q = 0; q < 4; ++q) {
    cc[q] = -1; nn[q] = -1; cs[q] = 0; ce[q] = 0;
    int i0 = q * 256 + tid;
    if (i0 < N) cc[q] = order[i0];
    int i1 = BATCH + q * 256 + tid;
    if (i1 < N) nn[q] = order[i1];
    if (cc[q] >= 0) { int2 sp = spans2[cc[q]]; cs[q] = sp.x; ce[q] = sp.y; }
  }

  int cnt = 0;
  for (int c0 = 0; c0 < N && cnt < k; c0 += BATCH) {
    // ---- prefetch next-round spans + next-next-round ids ----
    int pc[4], ps[4], pe[4];
    #pragma unroll
    for (int q = 0; q < 4; ++q) {
      pc[q] = nn[q]; ps[q] = 0; pe[q] = 0;
      if (pc[q] >= 0) { int2 sp = spans2[pc[q]]; ps[q] = sp.x; pe[q] = sp.y; }
      int i2 = c0 + 2 * BATCH + q * 256 + tid;
      nn[q] = (i2 < N) ? order[i2] : -1;
    }

    // ---- O(1) pre-check: 1 LDS read (R fresh as of end of last round) ----
    bool ok[4];
    unsigned long long bal[4];
    #pragma unroll
    for (int q = 0; q < 4; ++q) {
      ok[q] = (cc[q] >= 0) && !((R[cs[q]] >> (unsigned)(ce[q] - cs[q])) & 1u);
      bal[q] = __ballot(ok[q]);
      if (lane == 0) wvs[q * 4 + wave] = (int)__popcll(bal[q]);
    }
    __syncthreads();
    int qtot0 = wvs[0]  + wvs[1]  + wvs[2]  + wvs[3];
    int qtot1 = wvs[4]  + wvs[5]  + wvs[6]  + wvs[7];
    int qtot2 = wvs[8]  + wvs[9]  + wvs[10] + wvs[11];
    int qtot3 = wvs[12] + wvs[13] + wvs[14] + wvs[15];
    int ns = qtot0 + qtot1 + qtot2 + qtot3;

    if (ns > 0) {              // uniform branch: all threads agree on ns
      // ---- order-preserving survivor compression -> LDS (1024-wide) ----
      int qbase[4] = {0, qtot0, qtot0 + qtot1, qtot0 + qtot1 + qtot2};
      #pragma unroll
      for (int q = 0; q < 4; ++q) {
        if (ok[q]) {
          int wb = qbase[q];
          for (int w2 = 0; w2 < wave; ++w2) wb += wvs[q * 4 + w2];
          int pos = wb + (int)__popcll(bal[q] & ((1ull << lane) - 1ull));
          surv[pos] = ((unsigned long long)(unsigned)cs[q] << 48)
                    | ((unsigned long long)(unsigned)ce[q] << 32)
                    | (unsigned)cc[q];
        }
      }
      __syncthreads();

      // ---- parallel in-group crossing-matrix precompute (table-independent) ----
      for (int v = tid; v < ns; v += TPB) {
        unsigned long long pk = surv[v];
        int gs = (int)(pk >> 48), ge = (int)((pk >> 32) & 0xFFFFu);
        int gbase = v & ~63;
        int m = ns - gbase; if (m > 64) m = 64;
        unsigned long long C = 0;
        for (int j = 0; j < m; ++j) {
          unsigned long long pj = surv[gbase + j];
          int sj = (int)(pj >> 48), ej = (int)((pj >> 32) & 0xFFFFu);
          bool cr = (gs < sj && sj <= ge && ej > ge) ||
                    (sj < gs && gs <= ej && ej < ge);
          C |= (unsigned long long)cr << j;
        }
        Cmat[v] = C;
      }
      __syncthreads();

      const int cntPrev = cnt;
      // ---- wave-0 resolution, 64 survivors at a time (v3 verbatim) ----
      if (tid < 64) {
        bool dirty = false;    // any in-batch acceptance since pre-check?
        for (int g = 0; g < ns && cnt < k; g += 64) {
          int m = ns - g; if (m > 64) m = 64;
          bool act = lane < m;
          int gs = 0, ge = 0, gc = 0;
          unsigned long long C = 0;
          if (act) {
            unsigned long long pk = surv[g + lane];
            gs = (int)(pk >> 48);
            ge = (int)((pk >> 32) & 0xFFFFu);
            gc = (int)(unsigned)pk;
            C  = Cmat[g + lane];
          }
          bool pre = act;
          if (dirty) {         // re-check only when tables changed in-batch
            pre = act && precheck30(tabP, gc, gs, ge);
          }
          unsigned long long preB = __ballot(pre);
          if (preB == 0ull) continue;
          int np = (int)__popcll(preB);
          unsigned long long lower = (1ull << lane) - 1ull;
          unsigned long long accm;
          int cnt0g = cnt;
          if (np == 1) {                       // single-survivor fast path
            accm = preB;
            cnt += 1;
          } else {
            if (cnt + np <= k) {
              // bulk: accept all with no earlier *surviving* in-group crosser
              bool easy = pre && ((C & lower & preB) == 0ull);
              accm = __ballot(easy);
              unsigned long long rem = preB & ~accm;
              while (rem) {
                unsigned long long kmask = __ballot((C & accm & lower) != 0ull);
                int j = __ffsll((long long)rem) - 1;
                rem &= rem - 1;
                if (!((kmask >> j) & 1ull)) accm |= 1ull << j;
              }
              cnt += (int)__popcll(accm);
            } else {
              // k-cap mode: strict serial order incl. count limit
              accm = 0ull;
              unsigned long long rem = preB;
              while (rem && cnt < k) {
                unsigned long long kmask = __ballot((C & accm & lower) != 0ull);
                int j = __ffsll((long long)rem) - 1;
                rem &= rem - 1;
                if (!((kmask >> j) & 1ull)) { accm |= 1ull << j; cnt++; }
              }
            }
          }
          bool accme = ((accm >> lane) & 1ull) != 0ull;
          if (accme) {
            int rank = (int)__popcll(accm & lower);
            acc[cnt0g + rank] =
                ((unsigned long long)(unsigned)(gs * T + ge) << 32) | (unsigned)gc;
            racc_s[cnt0g + rank] = ((unsigned)gs << 16) | (unsigned)ge;
            atomicMax(&tab[gs].x, ge);
            atomicMin(&tab[ge].y, gs);
          }
          if (accme) {      // same-wave DS in-order: reads see all atomics
            int2 tv = tab[gs];
            tabP[gs] = ((unsigned)(tv.y > 65535 ? 65535 : tv.y) << 16)
                     | (unsigned)(tv.x + 1);
            int2 tv2 = tab[ge];
            tabP[ge] = ((unsigned)(tv2.y > 65535 ? 65535 : tv2.y) << 16)
                     | (unsigned)(tv2.x + 1);
          }
          if (accm) dirty = true;
        }
        if (lane == 0) gcnt = cnt;
      }
      __syncthreads();
      cnt = gcnt;

      // ---- BATCHED parallel R update: item = (accept, lane-offset) ----
      // accepted (as,ae), ae>as, rejects:
      //   s in [as-29, as-1]: w in [as-s, min(ae-1-s, 29)]
      //   s in [as+1,  ae  ]: w in [ae-s+1, min(T-1-s, 29)]
      // 64 offsets cover s in [as-29, as+34] (superset of the <=59 needed).
      {
        int nacc = cnt - cntPrev;
        for (int it = tid; it < nacc * 64; it += TPB) {
          unsigned pr = racc_s[cntPrev + (it >> 6)];
          int as = (int)(pr >> 16), ae = (int)(pr & 0xFFFFu);
          if (ae > as) {
            int s = as - MAXW + (it & 63);
            if (s >= 0 && s <= ae && s != as) {
              unsigned mmask = 0u;
              if (s < as) {
                int l1 = as - s;
                int h1 = ae - 1 - s; if (h1 > MAXW) h1 = MAXW;
                if (h1 >= l1)
                  mmask = ((1u << (h1 + 1)) - 1u) & ~((1u << l1) - 1u);
              } else {
                int l2 = ae - s + 1;
                int h2 = T - 1 - s; if (h2 > MAXW) h2 = MAXW;
                if (h2 >= l2)
                  mmask = ((1u << (h2 + 1)) - 1u) & ~((1u << l2) - 1u);
              }
              if (mmask) atomicOr(&R[s], mmask);
            }
          }
        }
      }
      __syncthreads();   // next round's pre-check reads R
    }

    #pragma unroll
    for (int q = 0; q < 4; ++q) { cc[q] = pc[q]; cs[q] = ps[q]; ce[q] = pe[q]; }
  }

  // ---- bitonic ascending sort of acc[0..cnt) by (s*T+e, cand) ----
  int M = 2;
  while (M < cnt) M <<= 1;
  for (int j = tid; j < M; j += TPB)
    if (j >= cnt) acc[j] = ~0ull;
  __syncthreads();
  for (int kk = 2; kk <= M; kk <<= 1) {
    for (int jj = kk >> 1; jj > 0; jj >>= 1) {
      for (int i3 = tid; i3 < M; i3 += TPB) {
        int ixj = i3 ^ jj;
        if (ixj > i3) {
          unsigned long long a = acc[i3], b = acc[ixj];
          bool up = ((i3 & kk) == 0);
          if ((a > b) == up) { acc[i3] = b; acc[ixj] = a; }
        }
      }
      __syncthreads();
    }
  }

  // ---- epilogue: scores | idx | spans | valid, all f32 ----
  for (int j = tid; j < k0; j += TPB) {
    if (j < cnt) {
      int cand = (int)(acc[j] & 0xFFFFFFFFu);
      out[j]                  = scores[cand];
      out[k0 + j]             = (float)cand;
      out[2 * k0 + 2 * j]     = (float)spans[2 * cand];
      out[2 * k0 + 2 * j + 1] = (float)spans[2 * cand + 1];
      out[4 * k0 + j]         = 1.0f;
    } else {
      out[j]                  = 0.0f;
      out[k0 + j]             = 0.0f;
      out[2 * k0 + 2 * j]     = 0.0f;
      out[2 * k0 + 2 * j + 1] = 0.0f;
      out[4 * k0 + j]         = 0.0f;
    }
  }
}

extern "C" void kernel_launch(void* const* d_in, const int* in_sizes, int n_in,
                              void* d_out, int out_size, void* d_ws, size_t ws_size,
                              hipStream_t stream) {
  const int*   spans  = (const int*)d_in[0];
  const float* scores = (const float*)d_in[1];
  const float* mask   = (const float*)d_in[2];
  const int*   tnum   = (const int*)d_in[3];
  const int*   keep   = (const int*)d_in[4];
  const int N = in_sizes[1];
  const int nT = (N + TILE - 1) / TILE;   // 60 for N=61440

  // ws: ctr[32] | ghist[4*256] | tileCnt[nT*256] | keysA | keysB | idxA | idxB
  unsigned* ctr     = (unsigned*)d_ws;
  unsigned* ghist   = ctr + 32;
  unsigned* tileCnt = ghist + 4 * 256;
  unsigned* keysA   = tileCnt + (size_t)nT * 256;
  unsigned* keysB   = keysA + N;
  int*      idxA    = (int*)(keysB + N);
  int*      idxB    = idxA + N;
  float*    out     = (float*)d_out;

  hipMemsetAsync(ctr, 0, (32 + 4 * 256) * sizeof(unsigned), stream);

  sort_kernel<<<nT, TPB, 0, stream>>>(scores, mask, N, nT, ctr, ghist,
                                      tileCnt, keysA, keysB, idxA, idxB);
  greedy_kernel<<<1, TPB, 0, stream>>>((const int2*)spans, spans, scores,
                                       idxA, tnum, keep, out, N);
}

// Round 9
// 287.595 us; speedup vs baseline: 1.3351x; 1.1331x over previous
//
#include <hip/hip_runtime.h>
#include <math.h>
#include <limits.h>

#define TPB   256
#define TILE  1024          // items per block-tile (256 thr x 4 rounds)
#define RNDS  4
#define MAXT  2048
#define TPAD  64            // pad so unconditional reads past e stay in-bounds
#define MAXK  1024
#define MAXW  29            // max span width in this problem (W=30 -> w<=29)
#define BATCH 1024          // greedy candidates per round (4 per thread)

// ===========================================================================
// Kernel A: fused key-build + 4-pass LSD radix argsort (60 blocks, grid bars)
// v9: merged rank rounds (1 scan/pass, ~4 barriers instead of ~16) +
//     per-wave shfl digit-base scans (0 barriers instead of 32).
// ===========================================================================
struct SortSM {
  union {
    unsigned h[4 * 256];                  // P0: 4 pass histograms
    struct {
      unsigned wcnt[16][256];             // [round*4+wave][digit], scanned in place
      unsigned baseL[256];
    } pass;
  };
};

// Device-scope grid barrier. SAFE: grid (<=60 blocks) fully co-resident on
// 256 CUs. ctr[] zeroed by memset node each launch.
__device__ inline void gbar(unsigned* ctr, int idx, unsigned nblk) {
  __syncthreads();
  if (threadIdx.x == 0) {
    __threadfence();
    atomicAdd(&ctr[idx], 1u);
    while (atomicAdd(&ctr[idx], 0u) < nblk) { __builtin_amdgcn_s_sleep(8); }
    __threadfence();
  }
  __syncthreads();
}

__global__ void __launch_bounds__(TPB, 1) sort_kernel(
    const float* __restrict__ scores, const float* __restrict__ mask,
    int N, int nT, unsigned* ctr, unsigned* ghist, unsigned* tileCnt,
    unsigned* keysA, unsigned* keysB, int* idxA, int* idxB) {
  __shared__ SortSM s;
  __shared__ unsigned base4[4][256];      // per-block copy of scanned bases
  const int tid = threadIdx.x;
  const int lane = tid & 63;
  const int wave = tid >> 6;

  // ---- P0: build keys + all 4 histograms in one read ----
  for (int j = tid; j < 1024; j += TPB) s.h[j] = 0;
  __syncthreads();
  {
    const int tile0 = blockIdx.x * TILE;
    for (int r = 0; r < RNDS; ++r) {
      int i = tile0 + r * 256 + tid;
      if (i < N) {
        float kf = scores[i] + logf(mask[i]);          // mask==1 -> +0 exact
        unsigned u = __float_as_uint(kf);
        u = (u & 0x80000000u) ? ~u : (u | 0x80000000u);
        u = ~u;                                        // descending order
        keysA[i] = u;
        atomicAdd(&s.h[(u & 255u)], 1u);
        atomicAdd(&s.h[256 + ((u >> 8) & 255u)], 1u);
        atomicAdd(&s.h[512 + ((u >> 16) & 255u)], 1u);
        atomicAdd(&s.h[768 + (u >> 24)], 1u);
      }
    }
    __syncthreads();
    for (int j = tid; j < 1024; j += TPB)
      if (s.h[j]) atomicAdd(&ghist[j], s.h[j]);
  }
  gbar(ctr, 0, nT);

  // ---- digit-base exclusive scans: wave p scans pass p via shfl (no bars) --
  {
    const int p = wave;                    // 4 waves, 4 passes
    unsigned v0 = ghist[p * 256 + 4 * lane + 0];
    unsigned v1 = ghist[p * 256 + 4 * lane + 1];
    unsigned v2 = ghist[p * 256 + 4 * lane + 2];
    unsigned v3 = ghist[p * 256 + 4 * lane + 3];
    unsigned sum = v0 + v1 + v2 + v3;
    unsigned x = sum;
    for (int off = 1; off < 64; off <<= 1) {
      unsigned y = __shfl_up(x, off, 64);
      if (lane >= off) x += y;
    }
    unsigned excl = x - sum;               // exclusive over 4-bin chunks
    base4[p][4 * lane + 0] = excl;
    base4[p][4 * lane + 1] = excl + v0;
    base4[p][4 * lane + 2] = excl + v0 + v1;
    base4[p][4 * lane + 3] = excl + v0 + v1 + v2;
  }
  __syncthreads();

  // ---- 4 fused rank/scatter radix passes (merged rank rounds) ----
  for (int p = 0; p < 4; ++p) {
    const unsigned* srck = (p & 1) ? keysB : keysA;
    const int*      srci = (p & 1) ? idxB : idxA;     // p==0: payload = i
    unsigned*       dstk = (p & 1) ? keysA : keysB;
    int*            dsti = (p & 1) ? idxA : idxB;
    const int shift = 8 * p;
    const int tile0 = blockIdx.x * TILE;

    for (int j = tid; j < 16 * 256; j += TPB)
      (&s.pass.wcnt[0][0])[j] = 0;
    __syncthreads();

    unsigned key[RNDS]; int pay[RNDS]; unsigned rnk[RNDS];
    unsigned dig[RNDS]; bool val[RNDS];
    #pragma unroll
    for (int r = 0; r < RNDS; ++r) {       // all loads issued upfront
      int i = tile0 + r * 256 + tid;
      val[r] = (i < N);
      key[r] = val[r] ? srck[i] : 0u;
      pay[r] = val[r] ? ((p == 0) ? i : srci[i]) : 0;
    }
    #pragma unroll
    for (int r = 0; r < RNDS; ++r) {       // 32 independent ballots, no bars
      unsigned d = (key[r] >> shift) & 255u;
      dig[r] = d;
      unsigned long long mm = __ballot(val[r]);
      #pragma unroll
      for (int b = 0; b < 8; ++b) {
        unsigned long long bb = __ballot((d >> b) & 1u);
        mm &= ((d >> b) & 1u) ? bb : ~bb;
      }
      rnk[r] = (unsigned)__popcll(mm & ((1ull << lane) - 1ull));
      if (val[r] && rnk[r] == 0)
        s.pass.wcnt[r * 4 + wave][d] = (unsigned)__popcll(mm);
    }
    __syncthreads();
    {                                      // one 16-way scan per digit
      unsigned run = 0;
      #pragma unroll
      for (int g = 0; g < 16; ++g) {
        unsigned c = s.pass.wcnt[g][tid];
        s.pass.wcnt[g][tid] = run;
        run += c;
      }
      tileCnt[blockIdx.x * 256 + tid] = run;
    }
    gbar(ctr, 1 + 2 * p, nT);              // entry barrier covers the scan

    unsigned baseacc = base4[p][tid];
    for (int t = 0; t < blockIdx.x; ++t)
      baseacc += tileCnt[t * 256 + tid];
    s.pass.baseL[tid] = baseacc;
    __syncthreads();
    #pragma unroll
    for (int r = 0; r < RNDS; ++r) {
      if (val[r]) {
        unsigned d = dig[r];
        unsigned pos = s.pass.baseL[d] + s.pass.wcnt[r * 4 + wave][d] + rnk[r];
        dstk[pos] = key[r];
        dsti[pos] = pay[r];
      }
    }
    if (p < 3) gbar(ctr, 2 + 2 * p, nT);
  }
  // final order in idxA (A->B->A->B->A)
}

// ===========================================================================
// Kernel B: batched-speculative greedy (1 block, 256 threads) + epilogue.
// v9 = v3 structure (tabP dirty-recheck, per-lane table updates) with the
//      serial while(rem) group resolution replaced by a PARALLEL FIXPOINT:
//      each iteration resolves every lane whose earlier crossers are all
//      resolved (accept) or that is killed by an earlier accept (reject).
//      Iterations = crossing-DAG depth (~4-6) instead of ~1 per candidate.
// ===========================================================================
__device__ inline bool precheck30(const unsigned* tabP, int cc, int cs, int ce) {
  if (cc < 0) return false;
  int w = ce - cs;
  bool crossed = false;
  #pragma unroll
  for (int off = 0; off <= MAXW; ++off) {
    unsigned tv = tabP[cs + off];
    crossed |= ((off >= 1) & (off <= w) & ((tv & 0xFFFFu) > (unsigned)(ce + 1)))
             | ((off < w) & ((tv >> 16) < (unsigned)cs));
  }
  for (int off = MAXW + 1; off <= w; ++off) {   // generic fallback (unused)
    unsigned tv = tabP[cs + off];
    crossed |= ((tv & 0xFFFFu) > (unsigned)(ce + 1));
    if (off < w) crossed |= ((tv >> 16) < (unsigned)cs);
  }
  return !crossed;
}

__global__ void __launch_bounds__(TPB, 1) greedy_kernel(
    const int2* __restrict__ spans2, const int* __restrict__ spans,
    const float* __restrict__ scores, const int* __restrict__ order,
    const int* __restrict__ tnum_p, const int* __restrict__ keep_p,
    float* __restrict__ out, int N) {
  __shared__ unsigned tabP[MAXT + TPAD];  // hi16 = e2s(enc), lo16 = s2e+1
  __shared__ int2 tab[MAXT + TPAD];       // authoritative: .x=s2e, .y=e2s
  __shared__ unsigned long long acc[MAXK];
  __shared__ unsigned long long surv[BATCH];
  __shared__ unsigned long long Cmat[BATCH];   // in-group crossing rows
  __shared__ int wvs[16];                      // survivor counts [quarter][wave]
  __shared__ int gcnt;

  const int tid = threadIdx.x;
  const int lane = tid & 63;
  const int wave = tid >> 6;
  const int T  = tnum_p[0];
  const int k0 = keep_p[0];
  const int k  = (k0 < MAXK) ? k0 : MAXK;

  for (int t = tid; t < MAXT + TPAD; t += TPB) {
    tab[t] = make_int2(-1, INT_MAX);
    tabP[t] = 0xFFFF0000u;               // s2e+1 = 0, e2s_enc = 0xFFFF
  }
  if (tid == 0) gcnt = 0;
  __syncthreads();

  // Each thread owns candidates q*256+tid (q=0..3) of every round.
  // ids prefetched 2 rounds ahead, spans 1 round ahead. Static indexing only.
  int cc[4], cs[4], ce[4], nn[4];
  #pragma unroll
  for (int q = 0; q < 4; ++q) {
    cc[q] = -1; nn[q] = -1; cs[q] = 0; ce[q] = 0;
    int i0 = q * 256 + tid;
    if (i0 < N) cc[q] = order[i0];
    int i1 = BATCH + q * 256 + tid;
    if (i1 < N) nn[q] = order[i1];
    if (cc[q] >= 0) { int2 sp = spans2[cc[q]]; cs[q] = sp.x; ce[q] = sp.y; }
  }

  int cnt = 0;
  for (int c0 = 0; c0 < N && cnt < k; c0 += BATCH) {
    // ---- prefetch next-round spans + next-next-round ids ----
    int pc[4], ps[4], pe[4];
    #pragma unroll
    for (int q = 0; q < 4; ++q) {
      pc[q] = nn[q]; ps[q] = 0; pe[q] = 0;
      if (pc[q] >= 0) { int2 sp = spans2[pc[q]]; ps[q] = sp.x; pe[q] = sp.y; }
      int i2 = c0 + 2 * BATCH + q * 256 + tid;
      nn[q] = (i2 < N) ? order[i2] : -1;
    }

    // ---- parallel pre-check vs packed tables (monotone -> speculative) ----
    bool ok[4];
    unsigned long long bal[4];
    #pragma unroll
    for (int q = 0; q < 4; ++q) {
      ok[q] = precheck30(tabP, cc[q], cs[q], ce[q]);
      bal[q] = __ballot(ok[q]);
      if (lane == 0) wvs[q * 4 + wave] = (int)__popcll(bal[q]);
    }
    __syncthreads();
    int qtot0 = wvs[0]  + wvs[1]  + wvs[2]  + wvs[3];
    int qtot1 = wvs[4]  + wvs[5]  + wvs[6]  + wvs[7];
    int qtot2 = wvs[8]  + wvs[9]  + wvs[10] + wvs[11];
    int qtot3 = wvs[12] + wvs[13] + wvs[14] + wvs[15];
    int ns = qtot0 + qtot1 + qtot2 + qtot3;

    if (ns > 0) {              // uniform branch: all threads agree on ns
      // ---- order-preserving survivor compression -> LDS (1024-wide) ----
      int qbase[4] = {0, qtot0, qtot0 + qtot1, qtot0 + qtot1 + qtot2};
      #pragma unroll
      for (int q = 0; q < 4; ++q) {
        if (ok[q]) {
          int wb = qbase[q];
          for (int w2 = 0; w2 < wave; ++w2) wb += wvs[q * 4 + w2];
          int pos = wb + (int)__popcll(bal[q] & ((1ull << lane) - 1ull));
          surv[pos] = ((unsigned long long)(unsigned)cs[q] << 48)
                    | ((unsigned long long)(unsigned)ce[q] << 32)
                    | (unsigned)cc[q];
        }
      }
      __syncthreads();

      // ---- parallel in-group crossing-matrix precompute (table-independent) ----
      for (int v = tid; v < ns; v += TPB) {
        unsigned long long pk = surv[v];
        int gs = (int)(pk >> 48), ge = (int)((pk >> 32) & 0xFFFFu);
        int gbase = v & ~63;
        int m = ns - gbase; if (m > 64) m = 64;
        unsigned long long C = 0;
        for (int j = 0; j < m; ++j) {
          unsigned long long pj = surv[gbase + j];
          int sj = (int)(pj >> 48), ej = (int)((pj >> 32) & 0xFFFFu);
          bool cr = (gs < sj && sj <= ge && ej > ge) ||
                    (sj < gs && gs <= ej && ej < ge);
          C |= (unsigned long long)cr << j;
        }
        Cmat[v] = C;
      }
      __syncthreads();

      // ---- wave-0 resolution, 64 survivors at a time ----
      if (tid < 64) {
        bool dirty = false;    // any in-batch acceptance since pre-check?
        for (int g = 0; g < ns && cnt < k; g += 64) {
          int m = ns - g; if (m > 64) m = 64;
          bool act = lane < m;
          int gs = 0, ge = 0, gc = 0;
          unsigned long long C = 0;
          if (act) {
            unsigned long long pk = surv[g + lane];
            gs = (int)(pk >> 48);
            ge = (int)((pk >> 32) & 0xFFFFu);
            gc = (int)(unsigned)pk;
            C  = Cmat[g + lane];
          }
          bool pre = act;
          if (dirty) {         // re-check only when tables changed in-batch
            pre = act && precheck30(tabP, gc, gs, ge);
          }
          unsigned long long preB = __ballot(pre);
          if (preB == 0ull) continue;
          int np = (int)__popcll(preB);
          unsigned long long lower = (1ull << lane) - 1ull;
          unsigned long long accm;
          int cnt0g = cnt;
          if (np == 1) {                       // single-survivor fast path
            accm = preB;
            cnt += 1;
          } else {
            // ---- parallel fixpoint: resolve ready lanes each iteration ----
            unsigned long long Cl = C & lower;        // my earlier crossers
            unsigned long long resolvedB = ~preB;     // non-pre start rejected
            accm = 0ull;
            while (true) {
              bool meUn   = ((resolvedB >> lane) & 1ull) == 0ull;
              bool killed = (Cl & accm) != 0ull;
              bool ready  = (Cl & ~resolvedB) == 0ull;
              unsigned long long newacc = __ballot(meUn && ready && !killed);
              unsigned long long newrej = __ballot(meUn && killed);
              if (!(newacc | newrej)) break;
              accm |= newacc;
              resolvedB |= (newacc | newrej);
            }
            int nacc = (int)__popcll(accm);
            if (cnt + nacc > k) {              // k-cap: keep first (k-cnt)
              int room = k - cnt;
              bool a0 = ((accm >> lane) & 1ull) != 0ull;
              int ar = (int)__popcll(accm & lower);
              accm = __ballot(a0 && (ar < room));
              nacc = room;
            }
            cnt += nacc;
          }
          bool accme = ((accm >> lane) & 1ull) != 0ull;
          if (accme) {
            int rank = (int)__popcll(accm & lower);
            acc[cnt0g + rank] =
                ((unsigned long long)(unsigned)(gs * T + ge) << 32) | (unsigned)gc;
            atomicMax(&tab[gs].x, ge);
            atomicMin(&tab[ge].y, gs);
          }
          if (accme) {      // same-wave DS in-order: reads see all atomics
            int2 tv = tab[gs];
            tabP[gs] = ((unsigned)(tv.y > 65535 ? 65535 : tv.y) << 16)
                     | (unsigned)(tv.x + 1);
            int2 tv2 = tab[ge];
            tabP[ge] = ((unsigned)(tv2.y > 65535 ? 65535 : tv2.y) << 16)
                     | (unsigned)(tv2.x + 1);
          }
          if (accm) dirty = true;
        }
        if (lane == 0) gcnt = cnt;
      }
      __syncthreads();
      cnt = gcnt;
    }

    #pragma unroll
    for (int q = 0; q < 4; ++q) { cc[q] = pc[q]; cs[q] = ps[q]; ce[q] = pe[q]; }
  }

  // ---- bitonic ascending sort of acc[0..cnt) by (s*T+e, cand) ----
  int M = 2;
  while (M < cnt) M <<= 1;
  for (int j = tid; j < M; j += TPB)
    if (j >= cnt) acc[j] = ~0ull;
  __syncthreads();
  for (int kk = 2; kk <= M; kk <<= 1) {
    for (int jj = kk >> 1; jj > 0; jj >>= 1) {
      for (int i3 = tid; i3 < M; i3 += TPB) {
        int ixj = i3 ^ jj;
        if (ixj > i3) {
          unsigned long long a = acc[i3], b = acc[ixj];
          bool up = ((i3 & kk) == 0);
          if ((a > b) == up) { acc[i3] = b; acc[ixj] = a; }
        }
      }
      __syncthreads();
    }
  }

  // ---- epilogue: scores | idx | spans | valid, all f32 ----
  for (int j = tid; j < k0; j += TPB) {
    if (j < cnt) {
      int cand = (int)(acc[j] & 0xFFFFFFFFu);
      out[j]                  = scores[cand];
      out[k0 + j]             = (float)cand;
      out[2 * k0 + 2 * j]     = (float)spans[2 * cand];
      out[2 * k0 + 2 * j + 1] = (float)spans[2 * cand + 1];
      out[4 * k0 + j]         = 1.0f;
    } else {
      out[j]                  = 0.0f;
      out[k0 + j]             = 0.0f;
      out[2 * k0 + 2 * j]     = 0.0f;
      out[2 * k0 + 2 * j + 1] = 0.0f;
      out[4 * k0 + j]         = 0.0f;
    }
  }
}

extern "C" void kernel_launch(void* const* d_in, const int* in_sizes, int n_in,
                              void* d_out, int out_size, void* d_ws, size_t ws_size,
                              hipStream_t stream) {
  const int*   spans  = (const int*)d_in[0];
  const float* scores = (const float*)d_in[1];
  const float* mask   = (const float*)d_in[2];
  const int*   tnum   = (const int*)d_in[3];
  const int*   keep   = (const int*)d_in[4];
  const int N = in_sizes[1];
  const int nT = (N + TILE - 1) / TILE;   // 60 for N=61440

  // ws: ctr[32] | ghist[4*256] | tileCnt[nT*256] | keysA | keysB | idxA | idxB
  unsigned* ctr     = (unsigned*)d_ws;
  unsigned* ghist   = ctr + 32;
  unsigned* tileCnt = ghist + 4 * 256;
  unsigned* keysA   = tileCnt + (size_t)nT * 256;
  unsigned* keysB   = keysA + N;
  int*      idxA    = (int*)(keysB + N);
  int*      idxB    = idxA + N;
  float*    out     = (float*)d_out;

  hipMemsetAsync(ctr, 0, (32 + 4 * 256) * sizeof(unsigned), stream);

  sort_kernel<<<nT, TPB, 0, stream>>>(scores, mask, N, nT, ctr, ghist,
                                      tileCnt, keysA, keysB, idxA, idxB);
  greedy_kernel<<<1, TPB, 0, stream>>>((const int2*)spans, spans, scores,
                                       idxA, tnum, keep, out, N);
}

// Round 10
// 242.883 us; speedup vs baseline: 1.5809x; 1.1841x over previous
//
#include <hip/hip_runtime.h>
#include <math.h>
#include <limits.h>

#define TPB   1024          // 16 waves/block = 4 waves/SIMD (latency hiding)
#define TILE  1024          // sort: 1 element per thread
#define MAXT  2048
#define TPAD  64            // pad so unconditional reads past e stay in-bounds
#define MAXK  1024
#define MAXW  29            // max span width in this problem (W=30 -> w<=29)
#define BATCH 1024          // greedy candidates per round (1 per thread)

// ===========================================================================
// Kernel A: fused key-build + 4-pass LSD radix argsort (60 blocks x 1024 thr)
// v10: 1 element/thread (no round loop), 16-wave ballot ranking.
// ===========================================================================
struct SortSM {
  union {
    unsigned h[4 * 256];                  // P0: 4 pass histograms
    unsigned wcnt[16][256];               // [wave][digit], scanned in place
  };
  unsigned baseL[256];
};

// Device-scope grid barrier. SAFE: grid (60 blocks, 16 waves each) fully
// co-resident on 256 CUs. ctr[] zeroed by memset node each launch.
__device__ inline void gbar(unsigned* ctr, int idx, unsigned nblk) {
  __syncthreads();
  if (threadIdx.x == 0) {
    __threadfence();
    atomicAdd(&ctr[idx], 1u);
    while (atomicAdd(&ctr[idx], 0u) < nblk) { __builtin_amdgcn_s_sleep(8); }
    __threadfence();
  }
  __syncthreads();
}

__global__ void __launch_bounds__(TPB, 4) sort_kernel(
    const float* __restrict__ scores, const float* __restrict__ mask,
    int N, int nT, unsigned* ctr, unsigned* ghist, unsigned* tileCnt,
    unsigned* keysA, unsigned* keysB, int* idxA, int* idxB) {
  __shared__ SortSM s;
  __shared__ unsigned base4[4][256];      // per-block copy of scanned bases
  const int tid = threadIdx.x;
  const int lane = tid & 63;
  const int wave = tid >> 6;              // 0..15

  // ---- P0: build keys + all 4 histograms in one read ----
  if (tid < 1024) s.h[tid] = 0;
  __syncthreads();
  {
    int i = blockIdx.x * TILE + tid;
    if (i < N) {
      float kf = scores[i] + logf(mask[i]);            // mask==1 -> +0 exact
      unsigned u = __float_as_uint(kf);
      u = (u & 0x80000000u) ? ~u : (u | 0x80000000u);
      u = ~u;                                          // descending order
      keysA[i] = u;
      atomicAdd(&s.h[(u & 255u)], 1u);
      atomicAdd(&s.h[256 + ((u >> 8) & 255u)], 1u);
      atomicAdd(&s.h[512 + ((u >> 16) & 255u)], 1u);
      atomicAdd(&s.h[768 + (u >> 24)], 1u);
    }
    __syncthreads();
    if (tid < 1024 && s.h[tid]) atomicAdd(&ghist[tid], s.h[tid]);
  }
  gbar(ctr, 0, nT);

  // ---- digit-base exclusive scans: wave p (p<4) scans pass p via shfl ----
  if (wave < 4) {
    const int p = wave;
    unsigned v0 = ghist[p * 256 + 4 * lane + 0];
    unsigned v1 = ghist[p * 256 + 4 * lane + 1];
    unsigned v2 = ghist[p * 256 + 4 * lane + 2];
    unsigned v3 = ghist[p * 256 + 4 * lane + 3];
    unsigned sum = v0 + v1 + v2 + v3;
    unsigned x = sum;
    for (int off = 1; off < 64; off <<= 1) {
      unsigned y = __shfl_up(x, off, 64);
      if (lane >= off) x += y;
    }
    unsigned excl = x - sum;               // exclusive over 4-bin chunks
    base4[p][4 * lane + 0] = excl;
    base4[p][4 * lane + 1] = excl + v0;
    base4[p][4 * lane + 2] = excl + v0 + v1;
    base4[p][4 * lane + 3] = excl + v0 + v1 + v2;
  }
  __syncthreads();

  // ---- 4 fused rank/scatter radix passes (1 element per thread) ----
  for (int p = 0; p < 4; ++p) {
    const unsigned* srck = (p & 1) ? keysB : keysA;
    const int*      srci = (p & 1) ? idxB : idxA;     // p==0: payload = i
    unsigned*       dstk = (p & 1) ? keysA : keysB;
    int*            dsti = (p & 1) ? idxA : idxB;
    const int shift = 8 * p;

    for (int j = tid; j < 16 * 256; j += TPB)
      (&s.wcnt[0][0])[j] = 0;
    __syncthreads();

    int i = blockIdx.x * TILE + tid;
    bool v = (i < N);
    unsigned key = v ? srck[i] : 0u;
    int pay = v ? ((p == 0) ? i : srci[i]) : 0;
    unsigned d = (key >> shift) & 255u;
    unsigned long long mm = __ballot(v);     // stable rank within wave
    #pragma unroll
    for (int b = 0; b < 8; ++b) {
      unsigned long long bb = __ballot((d >> b) & 1u);
      mm &= ((d >> b) & 1u) ? bb : ~bb;
    }
    unsigned rnk = (unsigned)__popcll(mm & ((1ull << lane) - 1ull));
    if (v && rnk == 0) s.wcnt[wave][d] = (unsigned)__popcll(mm);
    __syncthreads();
    if (tid < 256) {                       // one 16-way scan per digit
      unsigned run = 0;
      #pragma unroll
      for (int g = 0; g < 16; ++g) {
        unsigned c = s.wcnt[g][tid];
        s.wcnt[g][tid] = run;
        run += c;
      }
      tileCnt[blockIdx.x * 256 + tid] = run;
    }
    gbar(ctr, 1 + 2 * p, nT);              // entry barrier covers the scan

    if (tid < 256) {
      unsigned baseacc = base4[p][tid];
      for (int t = 0; t < blockIdx.x; ++t)
        baseacc += tileCnt[t * 256 + tid];
      s.baseL[tid] = baseacc;
    }
    __syncthreads();
    if (v) {
      unsigned pos = s.baseL[d] + s.wcnt[wave][d] + rnk;
      dstk[pos] = key;
      dsti[pos] = pay;
    }
    if (p < 3) gbar(ctr, 2 + 2 * p, nT);
  }
  // final order in idxA (A->B->A->B->A)
}

// ===========================================================================
// Kernel B: batched-speculative greedy (1 block, 1024 threads) + epilogue.
// v10 = v9 semantics at 16 waves (4/SIMD): 1 candidate/thread, wave-0
//       resolution with parallel fixpoint, tabP dirty-recheck.
// ===========================================================================
__device__ inline bool precheck30(const unsigned* tabP, int cc, int cs, int ce) {
  if (cc < 0) return false;
  int w = ce - cs;
  bool crossed = false;
  #pragma unroll
  for (int off = 0; off <= MAXW; ++off) {
    unsigned tv = tabP[cs + off];
    crossed |= ((off >= 1) & (off <= w) & ((tv & 0xFFFFu) > (unsigned)(ce + 1)))
             | ((off < w) & ((tv >> 16) < (unsigned)cs));
  }
  for (int off = MAXW + 1; off <= w; ++off) {   // generic fallback (unused)
    unsigned tv = tabP[cs + off];
    crossed |= ((tv & 0xFFFFu) > (unsigned)(ce + 1));
    if (off < w) crossed |= ((tv >> 16) < (unsigned)cs);
  }
  return !crossed;
}

__global__ void __launch_bounds__(TPB, 4) greedy_kernel(
    const int2* __restrict__ spans2, const int* __restrict__ spans,
    const float* __restrict__ scores, const int* __restrict__ order,
    const int* __restrict__ tnum_p, const int* __restrict__ keep_p,
    float* __restrict__ out, int N) {
  __shared__ unsigned tabP[MAXT + TPAD];  // hi16 = e2s(enc), lo16 = s2e+1
  __shared__ int2 tab[MAXT + TPAD];       // authoritative: .x=s2e, .y=e2s
  __shared__ unsigned long long acc[MAXK];
  __shared__ unsigned long long surv[BATCH];
  __shared__ unsigned long long Cmat[BATCH];   // in-group crossing rows
  __shared__ int wvs[16];                      // survivor count per wave
  __shared__ int gcnt;

  const int tid = threadIdx.x;
  const int lane = tid & 63;
  const int wave = tid >> 6;              // 0..15
  const int T  = tnum_p[0];
  const int k0 = keep_p[0];
  const int k  = (k0 < MAXK) ? k0 : MAXK;

  for (int t = tid; t < MAXT + TPAD; t += TPB) {
    tab[t] = make_int2(-1, INT_MAX);
    tabP[t] = 0xFFFF0000u;               // s2e+1 = 0, e2s_enc = 0xFFFF
  }
  if (tid == 0) gcnt = 0;
  __syncthreads();

  // Each thread owns candidate c0+tid of every round. ids prefetched 2
  // rounds ahead, spans 1 round ahead.
  int cc = -1, cs = 0, ce = 0, nn = -1;
  if (tid < N)         cc = order[tid];
  if (BATCH + tid < N) nn = order[BATCH + tid];
  if (cc >= 0) { int2 sp = spans2[cc]; cs = sp.x; ce = sp.y; }

  int cnt = 0;
  for (int c0 = 0; c0 < N && cnt < k; c0 += BATCH) {
    // ---- prefetch next-round span + next-next-round id ----
    int pc = nn, ps = 0, pe = 0;
    if (pc >= 0) { int2 sp = spans2[pc]; ps = sp.x; pe = sp.y; }
    int i2 = c0 + 2 * BATCH + tid;
    nn = (i2 < N) ? order[i2] : -1;

    // ---- parallel pre-check vs packed tables (monotone -> speculative) ----
    bool ok = precheck30(tabP, cc, cs, ce);
    unsigned long long bal = __ballot(ok);
    if (lane == 0) wvs[wave] = (int)__popcll(bal);
    __syncthreads();
    int ns = 0, wb = 0;
    #pragma unroll
    for (int w2 = 0; w2 < 16; ++w2) {
      if (w2 == wave) wb = ns;
      ns += wvs[w2];
    }

    if (ns > 0) {              // uniform branch: all threads agree on ns
      // ---- order-preserving survivor compression -> LDS ----
      if (ok) {
        int pos = wb + (int)__popcll(bal & ((1ull << lane) - 1ull));
        surv[pos] = ((unsigned long long)(unsigned)cs << 48)
                  | ((unsigned long long)(unsigned)ce << 32)
                  | (unsigned)cc;
      }
      __syncthreads();

      // ---- parallel in-group crossing-matrix precompute ----
      for (int v = tid; v < ns; v += TPB) {
        unsigned long long pk = surv[v];
        int gs = (int)(pk >> 48), ge = (int)((pk >> 32) & 0xFFFFu);
        int gbase = v & ~63;
        int m = ns - gbase; if (m > 64) m = 64;
        unsigned long long C = 0;
        for (int j = 0; j < m; ++j) {
          unsigned long long pj = surv[gbase + j];
          int sj = (int)(pj >> 48), ej = (int)((pj >> 32) & 0xFFFFu);
          bool cr = (gs < sj && sj <= ge && ej > ge) ||
                    (sj < gs && gs <= ej && ej < ge);
          C |= (unsigned long long)cr << j;
        }
        Cmat[v] = C;
      }
      __syncthreads();

      // ---- wave-0 resolution, 64 survivors at a time ----
      if (tid < 64) {
        bool dirty = false;    // any in-batch acceptance since pre-check?
        for (int g = 0; g < ns && cnt < k; g += 64) {
          int m = ns - g; if (m > 64) m = 64;
          bool act = lane < m;
          int gs = 0, ge = 0, gc = 0;
          unsigned long long C = 0;
          if (act) {
            unsigned long long pk = surv[g + lane];
            gs = (int)(pk >> 48);
            ge = (int)((pk >> 32) & 0xFFFFu);
            gc = (int)(unsigned)pk;
            C  = Cmat[g + lane];
          }
          bool pre = act;
          if (dirty) {         // re-check only when tables changed in-batch
            pre = act && precheck30(tabP, gc, gs, ge);
          }
          unsigned long long preB = __ballot(pre);
          if (preB == 0ull) continue;
          int np = (int)__popcll(preB);
          unsigned long long lower = (1ull << lane) - 1ull;
          unsigned long long accm;
          int cnt0g = cnt;
          if (np == 1) {                       // single-survivor fast path
            accm = preB;
            cnt += 1;
          } else {
            // ---- parallel fixpoint: resolve ready lanes each iteration ----
            unsigned long long Cl = C & lower;        // my earlier crossers
            unsigned long long resolvedB = ~preB;     // non-pre start rejected
            accm = 0ull;
            while (true) {
              bool meUn   = ((resolvedB >> lane) & 1ull) == 0ull;
              bool killed = (Cl & accm) != 0ull;
              bool ready  = (Cl & ~resolvedB) == 0ull;
              unsigned long long newacc = __ballot(meUn && ready && !killed);
              unsigned long long newrej = __ballot(meUn && killed);
              if (!(newacc | newrej)) break;
              accm |= newacc;
              resolvedB |= (newacc | newrej);
            }
            int nacc = (int)__popcll(accm);
            if (cnt + nacc > k) {              // k-cap: keep first (k-cnt)
              int room = k - cnt;
              bool a0 = ((accm >> lane) & 1ull) != 0ull;
              int ar = (int)__popcll(accm & lower);
              accm = __ballot(a0 && (ar < room));
              nacc = room;
            }
            cnt += nacc;
          }
          bool accme = ((accm >> lane) & 1ull) != 0ull;
          if (accme) {
            int rank = (int)__popcll(accm & lower);
            acc[cnt0g + rank] =
                ((unsigned long long)(unsigned)(gs * T + ge) << 32) | (unsigned)gc;
            atomicMax(&tab[gs].x, ge);
            atomicMin(&tab[ge].y, gs);
          }
          if (accme) {      // same-wave DS in-order: reads see all atomics
            int2 tv = tab[gs];
            tabP[gs] = ((unsigned)(tv.y > 65535 ? 65535 : tv.y) << 16)
                     | (unsigned)(tv.x + 1);
            int2 tv2 = tab[ge];
            tabP[ge] = ((unsigned)(tv2.y > 65535 ? 65535 : tv2.y) << 16)
                     | (unsigned)(tv2.x + 1);
          }
          if (accm) dirty = true;
        }
        if (lane == 0) gcnt = cnt;
      }
      __syncthreads();
      cnt = gcnt;
    }

    cc = pc; cs = ps; ce = pe;
  }

  // ---- bitonic ascending sort of acc[0..cnt) by (s*T+e, cand) ----
  int M = 2;
  while (M < cnt) M <<= 1;
  for (int j = tid; j < M; j += TPB)
    if (j >= cnt) acc[j] = ~0ull;
  __syncthreads();
  for (int kk = 2; kk <= M; kk <<= 1) {
    for (int jj = kk >> 1; jj > 0; jj >>= 1) {
      for (int i3 = tid; i3 < M; i3 += TPB) {
        int ixj = i3 ^ jj;
        if (ixj > i3) {
          unsigned long long a = acc[i3], b = acc[ixj];
          bool up = ((i3 & kk) == 0);
          if ((a > b) == up) { acc[i3] = b; acc[ixj] = a; }
        }
      }
      __syncthreads();
    }
  }

  // ---- epilogue: scores | idx | spans | valid, all f32 ----
  for (int j = tid; j < k0; j += TPB) {
    if (j < cnt) {
      int cand = (int)(acc[j] & 0xFFFFFFFFu);
      out[j]                  = scores[cand];
      out[k0 + j]             = (float)cand;
      out[2 * k0 + 2 * j]     = (float)spans[2 * cand];
      out[2 * k0 + 2 * j + 1] = (float)spans[2 * cand + 1];
      out[4 * k0 + j]         = 1.0f;
    } else {
      out[j]                  = 0.0f;
      out[k0 + j]             = 0.0f;
      out[2 * k0 + 2 * j]     = 0.0f;
      out[2 * k0 + 2 * j + 1] = 0.0f;
      out[4 * k0 + j]         = 0.0f;
    }
  }
}

extern "C" void kernel_launch(void* const* d_in, const int* in_sizes, int n_in,
                              void* d_out, int out_size, void* d_ws, size_t ws_size,
                              hipStream_t stream) {
  const int*   spans  = (const int*)d_in[0];
  const float* scores = (const float*)d_in[1];
  const float* mask   = (const float*)d_in[2];
  const int*   tnum   = (const int*)d_in[3];
  const int*   keep   = (const int*)d_in[4];
  const int N = in_sizes[1];
  const int nT = (N + TILE - 1) / TILE;   // 60 for N=61440

  // ws: ctr[32] | ghist[4*256] | tileCnt[nT*256] | keysA | keysB | idxA | idxB
  unsigned* ctr     = (unsigned*)d_ws;
  unsigned* ghist   = ctr + 32;
  unsigned* tileCnt = ghist + 4 * 256;
  unsigned* keysA   = tileCnt + (size_t)nT * 256;
  unsigned* keysB   = keysA + N;
  int*      idxA    = (int*)(keysB + N);
  int*      idxB    = idxA + N;
  float*    out     = (float*)d_out;

  hipMemsetAsync(ctr, 0, (32 + 4 * 256) * sizeof(unsigned), stream);

  sort_kernel<<<nT, TPB, 0, stream>>>(scores, mask, N, nT, ctr, ghist,
                                      tileCnt, keysA, keysB, idxA, idxB);
  greedy_kernel<<<1, TPB, 0, stream>>>((const int2*)spans, spans, scores,
                                       idxA, tnum, keep, out, N);
}

// Round 11
// 237.863 us; speedup vs baseline: 1.6142x; 1.0211x over previous
//
#include <hip/hip_runtime.h>
#include <math.h>
#include <limits.h>

#define TPB   1024          // 16 waves/block = 4 waves/SIMD (latency hiding)
#define TILE  1024          // sort: 1 element per thread
#define MAXT  2048
#define TPAD  64            // pad so unconditional reads past e stay in-bounds
#define MAXK  1024
#define MAXW  29            // max span width in this problem (W=30 -> w<=29)
#define BATCH 1024          // greedy candidates per round (1 per thread)
#define FLAGSTRIDE 16       // words per lookback flag (64B line each)

// ===========================================================================
// Kernel A: fused key-build + 4-pass LSD radix argsort (60 blocks x 1024 thr)
// v11: decoupled lookback replaces the mid-pass grid barrier (block b only
//      needs tileCnt of blocks t<b). Full barriers: 9 -> 4.
// ===========================================================================
struct SortSM {
  union {
    unsigned h[4 * 256];                  // P0: 4 pass histograms
    unsigned wcnt[16][256];               // [wave][digit], scanned in place
  };
  unsigned baseL[256];
};

// Device-scope grid barrier. SAFE: grid (60 blocks, 16 waves each) fully
// co-resident on 256 CUs. ctr[] zeroed by memset node each launch.
__device__ inline void gbar(unsigned* ctr, int idx, unsigned nblk) {
  __syncthreads();
  if (threadIdx.x == 0) {
    __threadfence();
    atomicAdd(&ctr[idx], 1u);
    while (atomicAdd(&ctr[idx], 0u) < nblk) { __builtin_amdgcn_s_sleep(8); }
    __threadfence();
  }
  __syncthreads();
}

__global__ void __launch_bounds__(TPB, 4) sort_kernel(
    const float* __restrict__ scores, const float* __restrict__ mask,
    int N, int nT, unsigned* ctr, unsigned* pflag, unsigned* ghist,
    unsigned* tileCnt, unsigned* keysA, unsigned* keysB, int* idxA, int* idxB) {
  __shared__ SortSM s;
  __shared__ unsigned base4[4][256];      // per-block copy of scanned bases
  const int tid = threadIdx.x;
  const int lane = tid & 63;
  const int wave = tid >> 6;              // 0..15

  // ---- P0: build keys + all 4 histograms in one read ----
  if (tid < 1024) s.h[tid] = 0;
  __syncthreads();
  {
    int i = blockIdx.x * TILE + tid;
    if (i < N) {
      float kf = scores[i] + logf(mask[i]);            // mask==1 -> +0 exact
      unsigned u = __float_as_uint(kf);
      u = (u & 0x80000000u) ? ~u : (u | 0x80000000u);
      u = ~u;                                          // descending order
      keysA[i] = u;
      atomicAdd(&s.h[(u & 255u)], 1u);
      atomicAdd(&s.h[256 + ((u >> 8) & 255u)], 1u);
      atomicAdd(&s.h[512 + ((u >> 16) & 255u)], 1u);
      atomicAdd(&s.h[768 + (u >> 24)], 1u);
    }
    __syncthreads();
    if (tid < 1024 && s.h[tid]) atomicAdd(&ghist[tid], s.h[tid]);
  }
  gbar(ctr, 0, nT);

  // ---- digit-base exclusive scans: wave p (p<4) scans pass p via shfl ----
  if (wave < 4) {
    const int p = wave;
    unsigned v0 = ghist[p * 256 + 4 * lane + 0];
    unsigned v1 = ghist[p * 256 + 4 * lane + 1];
    unsigned v2 = ghist[p * 256 + 4 * lane + 2];
    unsigned v3 = ghist[p * 256 + 4 * lane + 3];
    unsigned sum = v0 + v1 + v2 + v3;
    unsigned x = sum;
    for (int off = 1; off < 64; off <<= 1) {
      unsigned y = __shfl_up(x, off, 64);
      if (lane >= off) x += y;
    }
    unsigned excl = x - sum;               // exclusive over 4-bin chunks
    base4[p][4 * lane + 0] = excl;
    base4[p][4 * lane + 1] = excl + v0;
    base4[p][4 * lane + 2] = excl + v0 + v1;
    base4[p][4 * lane + 3] = excl + v0 + v1 + v2;
  }
  __syncthreads();

  // ---- 4 fused rank/scatter radix passes (1 element per thread) ----
  for (int p = 0; p < 4; ++p) {
    const unsigned* srck = (p & 1) ? keysB : keysA;
    const int*      srci = (p & 1) ? idxB : idxA;     // p==0: payload = i
    unsigned*       dstk = (p & 1) ? keysA : keysB;
    int*            dsti = (p & 1) ? idxA : idxB;
    const int shift = 8 * p;
    unsigned* flg = pflag + p * nT * FLAGSTRIDE;

    for (int j = tid; j < 16 * 256; j += TPB)
      (&s.wcnt[0][0])[j] = 0;
    __syncthreads();

    int i = blockIdx.x * TILE + tid;
    bool v = (i < N);
    unsigned key = v ? srck[i] : 0u;
    int pay = v ? ((p == 0) ? i : srci[i]) : 0;
    unsigned d = (key >> shift) & 255u;
    unsigned long long mm = __ballot(v);     // stable rank within wave
    #pragma unroll
    for (int b = 0; b < 8; ++b) {
      unsigned long long bb = __ballot((d >> b) & 1u);
      mm &= ((d >> b) & 1u) ? bb : ~bb;
    }
    unsigned rnk = (unsigned)__popcll(mm & ((1ull << lane) - 1ull));
    if (v && rnk == 0) s.wcnt[wave][d] = (unsigned)__popcll(mm);
    __syncthreads();
    if (tid < 256) {                       // one 16-way scan per digit
      unsigned run = 0;
      #pragma unroll
      for (int g = 0; g < 16; ++g) {
        unsigned c = s.wcnt[g][tid];
        s.wcnt[g][tid] = run;
        run += c;
      }
      tileCnt[blockIdx.x * 256 + tid] = run;
    }
    __syncthreads();                       // all tileCnt writes issued

    // ---- publish + decoupled lookback (replaces full grid barrier) ----
    if (tid == 0) {
      __threadfence();                     // release: tileCnt visible
      atomicExch(&flg[blockIdx.x * FLAGSTRIDE], 1u);
    }
    if (tid < blockIdx.x) {                // one thread polls one predecessor
      while (atomicAdd(&flg[tid * FLAGSTRIDE], 0u) == 0u)
        __builtin_amdgcn_s_sleep(2);
    }
    __syncthreads();
    if (tid == 0) __threadfence();         // acquire: invalidate stale lines
    __syncthreads();

    if (tid < 256) {
      unsigned baseacc = base4[p][tid];
      for (int t = 0; t < blockIdx.x; ++t)
        baseacc += tileCnt[t * 256 + tid];
      s.baseL[tid] = baseacc;
    }
    __syncthreads();
    if (v) {
      unsigned pos = s.baseL[d] + s.wcnt[wave][d] + rnk;
      dstk[pos] = key;
      dsti[pos] = pay;
    }
    if (p < 3) gbar(ctr, 1 + p, nT);       // scatter-complete: full barrier
  }
  // final order in idxA (A->B->A->B->A)
}

// ===========================================================================
// Kernel B: batched-speculative greedy (1 block, 1024 threads) + epilogue.
// v10 (unchanged): 1 candidate/thread, wave-0 resolution with parallel
// fixpoint, tabP dirty-recheck. 16 waves = 4/SIMD.
// ===========================================================================
__device__ inline bool precheck30(const unsigned* tabP, int cc, int cs, int ce) {
  if (cc < 0) return false;
  int w = ce - cs;
  bool crossed = false;
  #pragma unroll
  for (int off = 0; off <= MAXW; ++off) {
    unsigned tv = tabP[cs + off];
    crossed |= ((off >= 1) & (off <= w) & ((tv & 0xFFFFu) > (unsigned)(ce + 1)))
             | ((off < w) & ((tv >> 16) < (unsigned)cs));
  }
  for (int off = MAXW + 1; off <= w; ++off) {   // generic fallback (unused)
    unsigned tv = tabP[cs + off];
    crossed |= ((tv & 0xFFFFu) > (unsigned)(ce + 1));
    if (off < w) crossed |= ((tv >> 16) < (unsigned)cs);
  }
  return !crossed;
}

__global__ void __launch_bounds__(TPB, 4) greedy_kernel(
    const int2* __restrict__ spans2, const int* __restrict__ spans,
    const float* __restrict__ scores, const int* __restrict__ order,
    const int* __restrict__ tnum_p, const int* __restrict__ keep_p,
    float* __restrict__ out, int N) {
  __shared__ unsigned tabP[MAXT + TPAD];  // hi16 = e2s(enc), lo16 = s2e+1
  __shared__ int2 tab[MAXT + TPAD];       // authoritative: .x=s2e, .y=e2s
  __shared__ unsigned long long acc[MAXK];
  __shared__ unsigned long long surv[BATCH];
  __shared__ unsigned long long Cmat[BATCH];   // in-group crossing rows
  __shared__ int wvs[16];                      // survivor count per wave
  __shared__ int gcnt;

  const int tid = threadIdx.x;
  const int lane = tid & 63;
  const int wave = tid >> 6;              // 0..15
  const int T  = tnum_p[0];
  const int k0 = keep_p[0];
  const int k  = (k0 < MAXK) ? k0 : MAXK;

  for (int t = tid; t < MAXT + TPAD; t += TPB) {
    tab[t] = make_int2(-1, INT_MAX);
    tabP[t] = 0xFFFF0000u;               // s2e+1 = 0, e2s_enc = 0xFFFF
  }
  if (tid == 0) gcnt = 0;
  __syncthreads();

  // Each thread owns candidate c0+tid of every round. ids prefetched 2
  // rounds ahead, spans 1 round ahead.
  int cc = -1, cs = 0, ce = 0, nn = -1;
  if (tid < N)         cc = order[tid];
  if (BATCH + tid < N) nn = order[BATCH + tid];
  if (cc >= 0) { int2 sp = spans2[cc]; cs = sp.x; ce = sp.y; }

  int cnt = 0;
  for (int c0 = 0; c0 < N && cnt < k; c0 += BATCH) {
    // ---- prefetch next-round span + next-next-round id ----
    int pc = nn, ps = 0, pe = 0;
    if (pc >= 0) { int2 sp = spans2[pc]; ps = sp.x; pe = sp.y; }
    int i2 = c0 + 2 * BATCH + tid;
    nn = (i2 < N) ? order[i2] : -1;

    // ---- parallel pre-check vs packed tables (monotone -> speculative) ----
    bool ok = precheck30(tabP, cc, cs, ce);
    unsigned long long bal = __ballot(ok);
    if (lane == 0) wvs[wave] = (int)__popcll(bal);
    __syncthreads();
    int ns = 0, wb = 0;
    #pragma unroll
    for (int w2 = 0; w2 < 16; ++w2) {
      if (w2 == wave) wb = ns;
      ns += wvs[w2];
    }

    if (ns > 0) {              // uniform branch: all threads agree on ns
      // ---- order-preserving survivor compression -> LDS ----
      if (ok) {
        int pos = wb + (int)__popcll(bal & ((1ull << lane) - 1ull));
        surv[pos] = ((unsigned long long)(unsigned)cs << 48)
                  | ((unsigned long long)(unsigned)ce << 32)
                  | (unsigned)cc;
      }
      __syncthreads();

      // ---- parallel in-group crossing-matrix precompute ----
      for (int v = tid; v < ns; v += TPB) {
        unsigned long long pk = surv[v];
        int gs = (int)(pk >> 48), ge = (int)((pk >> 32) & 0xFFFFu);
        int gbase = v & ~63;
        int m = ns - gbase; if (m > 64) m = 64;
        unsigned long long C = 0;
        for (int j = 0; j < m; ++j) {
          unsigned long long pj = surv[gbase + j];
          int sj = (int)(pj >> 48), ej = (int)((pj >> 32) & 0xFFFFu);
          bool cr = (gs < sj && sj <= ge && ej > ge) ||
                    (sj < gs && gs <= ej && ej < ge);
          C |= (unsigned long long)cr << j;
        }
        Cmat[v] = C;
      }
      __syncthreads();

      // ---- wave-0 resolution, 64 survivors at a time ----
      if (tid < 64) {
        bool dirty = false;    // any in-batch acceptance since pre-check?
        for (int g = 0; g < ns && cnt < k; g += 64) {
          int m = ns - g; if (m > 64) m = 64;
          bool act = lane < m;
          int gs = 0, ge = 0, gc = 0;
          unsigned long long C = 0;
          if (act) {
            unsigned long long pk = surv[g + lane];
            gs = (int)(pk >> 48);
            ge = (int)((pk >> 32) & 0xFFFFu);
            gc = (int)(unsigned)pk;
            C  = Cmat[g + lane];
          }
          bool pre = act;
          if (dirty) {         // re-check only when tables changed in-batch
            pre = act && precheck30(tabP, gc, gs, ge);
          }
          unsigned long long preB = __ballot(pre);
          if (preB == 0ull) continue;
          int np = (int)__popcll(preB);
          unsigned long long lower = (1ull << lane) - 1ull;
          unsigned long long accm;
          int cnt0g = cnt;
          if (np == 1) {                       // single-survivor fast path
            accm = preB;
            cnt += 1;
          } else {
            // ---- parallel fixpoint: resolve ready lanes each iteration ----
            unsigned long long Cl = C & lower;        // my earlier crossers
            unsigned long long resolvedB = ~preB;     // non-pre start rejected
            accm = 0ull;
            while (true) {
              bool meUn   = ((resolvedB >> lane) & 1ull) == 0ull;
              bool killed = (Cl & accm) != 0ull;
              bool ready  = (Cl & ~resolvedB) == 0ull;
              unsigned long long newacc = __ballot(meUn && ready && !killed);
              unsigned long long newrej = __ballot(meUn && killed);
              if (!(newacc | newrej)) break;
              accm |= newacc;
              resolvedB |= (newacc | newrej);
            }
            int nacc = (int)__popcll(accm);
            if (cnt + nacc > k) {              // k-cap: keep first (k-cnt)
              int room = k - cnt;
              bool a0 = ((accm >> lane) & 1ull) != 0ull;
              int ar = (int)__popcll(accm & lower);
              accm = __ballot(a0 && (ar < room));
              nacc = room;
            }
            cnt += nacc;
          }
          bool accme = ((accm >> lane) & 1ull) != 0ull;
          if (accme) {
            int rank = (int)__popcll(accm & lower);
            acc[cnt0g + rank] =
                ((unsigned long long)(unsigned)(gs * T + ge) << 32) | (unsigned)gc;
            atomicMax(&tab[gs].x, ge);
            atomicMin(&tab[ge].y, gs);
          }
          if (accme) {      // same-wave DS in-order: reads see all atomics
            int2 tv = tab[gs];
            tabP[gs] = ((unsigned)(tv.y > 65535 ? 65535 : tv.y) << 16)
                     | (unsigned)(tv.x + 1);
            int2 tv2 = tab[ge];
            tabP[ge] = ((unsigned)(tv2.y > 65535 ? 65535 : tv2.y) << 16)
                     | (unsigned)(tv2.x + 1);
          }
          if (accm) dirty = true;
        }
        if (lane == 0) gcnt = cnt;
      }
      __syncthreads();
      cnt = gcnt;
    }

    cc = pc; cs = ps; ce = pe;
  }

  // ---- bitonic ascending sort of acc[0..cnt) by (s*T+e, cand) ----
  int M = 2;
  while (M < cnt) M <<= 1;
  for (int j = tid; j < M; j += TPB)
    if (j >= cnt) acc[j] = ~0ull;
  __syncthreads();
  for (int kk = 2; kk <= M; kk <<= 1) {
    for (int jj = kk >> 1; jj > 0; jj >>= 1) {
      for (int i3 = tid; i3 < M; i3 += TPB) {
        int ixj = i3 ^ jj;
        if (ixj > i3) {
          unsigned long long a = acc[i3], b = acc[ixj];
          bool up = ((i3 & kk) == 0);
          if ((a > b) == up) { acc[i3] = b; acc[ixj] = a; }
        }
      }
      __syncthreads();
    }
  }

  // ---- epilogue: scores | idx | spans | valid, all f32 ----
  for (int j = tid; j < k0; j += TPB) {
    if (j < cnt) {
      int cand = (int)(acc[j] & 0xFFFFFFFFu);
      out[j]                  = scores[cand];
      out[k0 + j]             = (float)cand;
      out[2 * k0 + 2 * j]     = (float)spans[2 * cand];
      out[2 * k0 + 2 * j + 1] = (float)spans[2 * cand + 1];
      out[4 * k0 + j]         = 1.0f;
    } else {
      out[j]                  = 0.0f;
      out[k0 + j]             = 0.0f;
      out[2 * k0 + 2 * j]     = 0.0f;
      out[2 * k0 + 2 * j + 1] = 0.0f;
      out[4 * k0 + j]         = 0.0f;
    }
  }
}

extern "C" void kernel_launch(void* const* d_in, const int* in_sizes, int n_in,
                              void* d_out, int out_size, void* d_ws, size_t ws_size,
                              hipStream_t stream) {
  const int*   spans  = (const int*)d_in[0];
  const float* scores = (const float*)d_in[1];
  const float* mask   = (const float*)d_in[2];
  const int*   tnum   = (const int*)d_in[3];
  const int*   keep   = (const int*)d_in[4];
  const int N = in_sizes[1];
  const int nT = (N + TILE - 1) / TILE;   // 60 for N=61440

  // ws: ctr[32] | pflag[4*nT*FS] | ghist[1024] | tileCnt[nT*256] | keysA/B | idxA/B
  unsigned* ctr     = (unsigned*)d_ws;
  unsigned* pflag   = ctr + 32;
  unsigned* ghist   = pflag + (size_t)4 * nT * FLAGSTRIDE;
  unsigned* tileCnt = ghist + 1024;
  unsigned* keysA   = tileCnt + (size_t)nT * 256;
  unsigned* keysB   = keysA + N;
  int*      idxA    = (int*)(keysB + N);
  int*      idxB    = idxA + N;
  float*    out     = (float*)d_out;

  hipMemsetAsync(ctr, 0,
                 (32 + (size_t)4 * nT * FLAGSTRIDE + 1024) * sizeof(unsigned),
                 stream);

  sort_kernel<<<nT, TPB, 0, stream>>>(scores, mask, N, nT, ctr, pflag, ghist,
                                      tileCnt, keysA, keysB, idxA, idxB);
  greedy_kernel<<<1, TPB, 0, stream>>>((const int2*)spans, spans, scores,
                                       idxA, tnum, keep, out, N);
}